// Round 19
// baseline (142.188 us; speedup 1.0000x reference)
//
#include <hip/hip_runtime.h>
#include <hip/hip_bf16.h>
#include <cstdint>

typedef __attribute__((ext_vector_type(4))) float f32x4;
typedef __attribute__((ext_vector_type(8))) short bf16x8;

__device__ __forceinline__ ushort f2bf(float f) {
  unsigned u = __builtin_bit_cast(unsigned, f);
  u += 0x7fffu + ((u >> 16) & 1u);
  return (ushort)(u >> 16);
}

__device__ __forceinline__ void gload_lds16(const ushort* g, ushort* l) {
  __builtin_amdgcn_global_load_lds(
      (const __attribute__((address_space(1))) unsigned int*)g,
      (__attribute__((address_space(3))) unsigned int*)l, 16, 0, 0);
}

__device__ __forceinline__ void hard_barrier() {
  __builtin_amdgcn_sched_barrier(0);
  __builtin_amdgcn_s_barrier();
  __builtin_amdgcn_sched_barrier(0);
}

template <int N>
__device__ __forceinline__ void wait_vm() {
  if constexpr (N == 0) asm volatile("s_waitcnt vmcnt(0)" ::: "memory");
  else if constexpr (N == 2) asm volatile("s_waitcnt vmcnt(2)" ::: "memory");
  else if constexpr (N == 3) asm volatile("s_waitcnt vmcnt(3)" ::: "memory");
  else if constexpr (N == 4) asm volatile("s_waitcnt vmcnt(4)" ::: "memory");
  else static_assert(N < 0, "unsupported vmcnt");
}

__device__ __forceinline__ float elu1(float v) {
  return (v > 0.f) ? (v + 1.f) : __expf(v);
}

// ---------- kernel 0: fused prep (R10 verbatim) ----------
__global__ __launch_bounds__(256) void prep_kernel(const float4* __restrict__ x,
                                                   ushort4* __restrict__ xb,
                                                   const float* __restrict__ W,
                                                   ushort* __restrict__ Wt) {
  if (blockIdx.x < 2048) {
    const int n4 = 16384 * 1024 / 4;
    const int stride = 2048 * 256;
    for (int i = blockIdx.x * 256 + threadIdx.x; i < n4; i += stride) {
      float4 f = x[i];
      ushort4 o;
      o.x = f2bf(f.x); o.y = f2bf(f.y); o.z = f2bf(f.z); o.w = f2bf(f.w);
      xb[i] = o;
    }
  } else {
    __shared__ float tile[32][33];
    const int tb = blockIdx.x - 2048;     // 0..1535
    const int n0 = (tb % 48) * 32;
    const int k0 = (tb / 48) * 32;
    const int tx = threadIdx.x & 31;
    const int ty = threadIdx.x >> 5;      // 0..7
    #pragma unroll
    for (int p = 0; p < 4; ++p) {
      int k = k0 + ty + p * 8;
      tile[ty + p * 8][tx] = W[(size_t)k * 1536 + n0 + tx];
    }
    __syncthreads();
    #pragma unroll
    for (int p = 0; p < 4; ++p) {
      int n = n0 + ty + p * 8;
      Wt[(size_t)n * 1024 + k0 + tx] = f2bf(tile[tx][ty + p * 8]);
    }
  }
}

// ============================================================================
// R15 core (850 TF, 0 conflicts, 2 blocks/CU): 128x256 tile, 512 thr = 8
// waves (2M x 4N), wave tile 64x64, BK=32, 3 slots x 24KB = 72 KiB.
// Used by gemm_out (512-block grid = 1 exact round at 2/CU).
// ============================================================================
template <int LDA, int LDB, int NT>
__device__ __forceinline__ void gemm_core32(const ushort* __restrict__ A,
                                            const ushort* __restrict__ Bt,
                                            int row0, int col0, f32x4 acc[4][4],
                                            ushort* lds) {
  const int tid = threadIdx.x;
  const int l = tid & 63;
  const int wid = tid >> 6;
  const int fr = l & 15;
  const int fq = l >> 4;
  const int wr = wid >> 2;
  const int wc = wid & 3;

  const int sc = ((tid & 3) ^ ((tid >> 3) & 3)) * 8;  // pre-swizzled source col
  const ushort* aS = A + (size_t)(row0 + (tid >> 2)) * LDA + sc;
  const ushort* bS = Bt + (size_t)(col0 + (tid >> 2)) * LDB + sc;

  auto stage = [&](int t) {
    ushort* base = lds + (t % 3) * 12288 + tid * 8;
    gload_lds16(aS + t * 32, base);
    gload_lds16(bS + t * 32, base + 4096);
    gload_lds16(bS + (size_t)128 * LDB + t * 32, base + 8192);
  };

  const int sig = fq ^ ((fr >> 1) & 3);
  const int aOff = wr * 2048 + fr * 32 + sig * 8;
  const int bOff = 4096 + wc * 2048 + fr * 32 + sig * 8;

  auto compute = [&](int t) {
    const ushort* sb = lds + (t % 3) * 12288;
    bf16x8 av[4], bv[4];
    #pragma unroll
    for (int m = 0; m < 4; ++m) av[m] = *(const bf16x8*)(sb + aOff + m * 512);
    #pragma unroll
    for (int n = 0; n < 4; ++n) bv[n] = *(const bf16x8*)(sb + bOff + n * 512);
    __builtin_amdgcn_s_setprio(1);
    #pragma unroll
    for (int m = 0; m < 4; ++m)
      #pragma unroll
      for (int n = 0; n < 4; ++n)
        acc[m][n] = __builtin_amdgcn_mfma_f32_16x16x32_bf16(av[m], bv[n], acc[m][n], 0, 0, 0);
    __builtin_amdgcn_s_setprio(0);
  };

  stage(0);
  stage(1);
  wait_vm<3>();
  hard_barrier();

  #pragma unroll 3
  for (int t = 0; t < NT; ++t) {
    if (t + 2 < NT) stage(t + 2);
    compute(t);
    if (t + 2 < NT) {
      wait_vm<3>();
      hard_barrier();
    } else if (t + 1 < NT) {
      wait_vm<0>();
      hard_barrier();
    }
  }
}

// ============================================================================
// NEW qkv core: 128x128 tile, 256 thr = 4 waves (2x2, wave tile 64x64 — same
// 2.0 MFMA:ds_read ratio as R15). BK=32, 3 slots x 16KB = 48 KiB -> THREE
// blocks/CU (12 waves). Grid 128x12 = 1536 = EXACTLY 2 rounds of 768
// co-resident blocks: removes the 1.5-round tail that costs qkv a full
// half-empty round (makespan audit: R15 = 2xT2 with CUs half-idle in round 2).
// Schedule = R15's proven 3-slot counted pipeline: stage(t+2); compute(t);
// vmcnt(4) [4 gloads/thread/tile]; one barrier. Swizzle = R15's verified
// conflict-free pattern (sig = fq^((fr>>1)&3); source lam = (tid&3)^((tid>>3)&3);
// staging row-pass stride 64 is a multiple of 4 so lam holds for both passes).
// ============================================================================
template <int LDA, int LDB, int NT>
__device__ __forceinline__ void gemm_core128(const ushort* __restrict__ A,
                                             const ushort* __restrict__ Bt,
                                             int row0, int col0, f32x4 acc[4][4],
                                             ushort* lds) {
  const int tid = threadIdx.x;  // 0..255
  const int l = tid & 63;
  const int wid = tid >> 6;  // 0..3
  const int fr = l & 15;
  const int fq = l >> 4;
  const int wr = wid >> 1;
  const int wc = wid & 1;

  const int sc = ((tid & 3) ^ ((tid >> 3) & 3)) * 8;  // pre-swizzled source col
  const ushort* aS = A + (size_t)(row0 + (tid >> 2)) * LDA + sc;  // rows 0..63
  const ushort* bS = Bt + (size_t)(col0 + (tid >> 2)) * LDB + sc;

  auto stage = [&](int t) {
    ushort* base = lds + (t % 3) * 8192 + tid * 8;
    gload_lds16(aS + t * 32, base);
    gload_lds16(aS + (size_t)64 * LDA + t * 32, base + 2048);
    gload_lds16(bS + t * 32, base + 4096);
    gload_lds16(bS + (size_t)64 * LDB + t * 32, base + 6144);
  };

  const int sig = fq ^ ((fr >> 1) & 3);
  const int aOff = wr * 2048 + fr * 32 + sig * 8;          // + m*512
  const int bOff = 4096 + wc * 2048 + fr * 32 + sig * 8;   // + n*512

  auto compute = [&](int t) {
    const ushort* sb = lds + (t % 3) * 8192;
    bf16x8 av[4], bv[4];
    #pragma unroll
    for (int m = 0; m < 4; ++m) av[m] = *(const bf16x8*)(sb + aOff + m * 512);
    #pragma unroll
    for (int n = 0; n < 4; ++n) bv[n] = *(const bf16x8*)(sb + bOff + n * 512);
    __builtin_amdgcn_s_setprio(1);
    #pragma unroll
    for (int m = 0; m < 4; ++m)
      #pragma unroll
      for (int n = 0; n < 4; ++n)
        acc[m][n] = __builtin_amdgcn_mfma_f32_16x16x32_bf16(av[m], bv[n], acc[m][n], 0, 0, 0);
    __builtin_amdgcn_s_setprio(0);
  };

  stage(0);
  stage(1);
  wait_vm<4>();
  hard_barrier();

  #pragma unroll 4
  for (int t = 0; t < NT; ++t) {
    if (t + 2 < NT) stage(t + 2);
    compute(t);
    if (t + 2 < NT) {
      wait_vm<4>();
      hard_barrier();
    } else if (t + 1 < NT) {
      wait_vm<0>();
      hard_barrier();
    }
  }
}

// ---------- kernel 1: qkv GEMM (128x128, 3 blocks/CU, exact 2 rounds) ------
// col panels of 128 -> each block entirely within q / k / v region.
__global__ __launch_bounds__(256, 4) void gemm_qkv_kernel(const ushort* __restrict__ xb,
                                                          const ushort* __restrict__ wt,
                                                          ushort* __restrict__ q,
                                                          ushort* __restrict__ kT,
                                                          ushort* __restrict__ vT) {
  __shared__ ushort lds[24576];  // 48 KiB -> 3 blocks/CU
  f32x4 acc[4][4] = {};
  const int row0 = blockIdx.x * 128;
  const int col0 = blockIdx.y * 128;
  gemm_core128<1024, 1024, 32>(xb, wt, row0, col0, acc, lds);
  const int l = threadIdx.x & 63;
  const int wid = threadIdx.x >> 6;
  const int wr = wid >> 1, wc = wid & 1;
  const int fr = l & 15, fq = l >> 4;
  #pragma unroll
  for (int m = 0; m < 4; ++m) {
    #pragma unroll
    for (int n = 0; n < 4; ++n) {
      const int c = col0 + wc * 64 + n * 16 + fr;
      const int r0 = row0 + wr * 64 + m * 16 + fq * 4;  // j=0..3 consecutive rows
      if (c < 512) {
        #pragma unroll
        for (int j = 0; j < 4; ++j)
          q[(size_t)(r0 + j) * 512 + c] = f2bf(elu1(acc[m][n][j]));
      } else if (c < 1024) {
        const int d = c - 512;
        const int bh = (r0 >> 12) * 8 + (d >> 6);
        const int nn = r0 & 4095;
        ushort4 o;
        o.x = f2bf(elu1(acc[m][n][0]));
        o.y = f2bf(elu1(acc[m][n][1]));
        o.z = f2bf(elu1(acc[m][n][2]));
        o.w = f2bf(elu1(acc[m][n][3]));
        *(ushort4*)&kT[((size_t)bh * 64 + (d & 63)) * 4096 + nn] = o;
      } else {
        const int d = c - 1024;
        const int bh = (r0 >> 12) * 8 + (d >> 6);
        const int nn = r0 & 4095;
        ushort4 o;
        o.x = f2bf(acc[m][n][0]);
        o.y = f2bf(acc[m][n][1]);
        o.z = f2bf(acc[m][n][2]);
        o.w = f2bf(acc[m][n][3]);
        *(ushort4*)&vT[((size_t)bh * 64 + (d & 63)) * 4096 + nn] = o;
      }
    }
  }
}

// ---------- kernel 2: ctx partials via MFMA; 16 splits (R18 verbatim) ------
__global__ __launch_bounds__(256) void ctx_mfma_kernel(const ushort* __restrict__ kT,
                                                       const ushort* __restrict__ vT,
                                                       float* __restrict__ part) {
  __shared__ ushort lds[16384];  // 32 KiB
  const int bh = blockIdx.x;
  const int sp = blockIdx.y;  // 0..15
  const int tid = threadIdx.x;
  const int l = tid & 63, wid = tid >> 6;
  const int fr = l & 15, fq = l >> 4;
  const int wr = wid >> 1, wc = wid & 1;

  const size_t base = (size_t)bh * 64 * 4096 + sp * 256;
  const int srow = tid >> 2;                     // 0..63
  const int lam = (tid & 3) ^ ((tid >> 3) & 3);  // logical 16B slot for phys (tid&3)
  const ushort* aG = kT + base + (size_t)srow * 4096 + lam * 8;
  const ushort* bG = vT + base + (size_t)srow * 4096 + lam * 8;

  auto stage = [&](int t) {
    ushort* d = lds + (t & 3) * 4096 + tid * 8;
    gload_lds16(aG + t * 32, d);
    gload_lds16(bG + t * 32, d + 2048);
  };

  const int sig = fq ^ ((fr >> 1) & 3);
  f32x4 acc[2][2] = {};

  auto compute = [&](int t) {
    const ushort* sb = lds + (t & 3) * 4096;
    bf16x8 av[2], bv[2];
    #pragma unroll
    for (int mm = 0; mm < 2; ++mm)
      av[mm] = *(const bf16x8*)&sb[(wr * 32 + mm * 16 + fr) * 32 + sig * 8];
    #pragma unroll
    for (int nn = 0; nn < 2; ++nn)
      bv[nn] = *(const bf16x8*)&sb[2048 + (wc * 32 + nn * 16 + fr) * 32 + sig * 8];
    #pragma unroll
    for (int mm = 0; mm < 2; ++mm)
      #pragma unroll
      for (int nn = 0; nn < 2; ++nn)
        acc[mm][nn] = __builtin_amdgcn_mfma_f32_16x16x32_bf16(av[mm], bv[nn], acc[mm][nn], 0, 0, 0);
  };

  constexpr int NT = 8;
  stage(0); stage(1); stage(2);
  for (int t = 0; t < NT; ++t) {
    if (t <= NT - 3) wait_vm<4>();
    else if (t == NT - 2) wait_vm<2>();
    else wait_vm<0>();
    hard_barrier();
    compute(t);
    hard_barrier();
    if (t + 3 < NT) stage(t + 3);
  }

  float* dst = part + ((size_t)sp * 32 + bh) * 4096;
  #pragma unroll
  for (int mm = 0; mm < 2; ++mm)
    #pragma unroll
    for (int nn = 0; nn < 2; ++nn)
      #pragma unroll
      for (int j = 0; j < 4; ++j)
        dst[(wr * 32 + mm * 16 + fq * 4 + j) * 64 + wc * 32 + nn * 16 + fr] = acc[mm][nn][j];
}

// ---------- kernel 3: W_eff^T (folds the 16-way split reduction) ----------
__global__ __launch_bounds__(256) void weff_kernel(const float* __restrict__ part,
                                                   const float* __restrict__ Wout,
                                                   ushort* __restrict__ weff) {
  const int bh = blockIdx.x;  // b*8+h
  const int h = bh & 7;
  const int m0 = blockIdx.y * 128;
  const int t = threadIdx.x;
  __shared__ float cs[64 * 64];
  __shared__ float ws[64][128];
  #pragma unroll
  for (int p = 0; p < 4; ++p) {
    const int idx = p * 1024 + t * 4;
    f32x4 s = {};
    #pragma unroll
    for (int sp = 0; sp < 16; ++sp)
      s += *(const f32x4*)&part[(size_t)sp * 131072 + (size_t)bh * 4096 + idx];
    *(f32x4*)&cs[idx] = s;
  }
  #pragma unroll
  for (int p = 0; p < 8; ++p) {
    const int e = (t >> 5) + p * 8;
    const int c = (t & 31) * 4;
    *(float4*)&ws[e][c] = *(const float4*)&Wout[(size_t)(h * 64 + e) * 1024 + m0 + c];
  }
  __syncthreads();
  const int m = t & 127;
  const int dh = (t >> 7) * 32;
  float acc[32] = {};
  for (int e = 0; e < 64; ++e) {
    const float w = ws[e][m];
    #pragma unroll
    for (int i = 0; i < 32; ++i)
      acc[i] += cs[(dh + i) * 64 + e] * w;
  }
  ushort* dst = weff + ((size_t)(bh >> 3) * 1024 + m0 + m) * 512 + h * 64 + dh;
  #pragma unroll
  for (int i = 0; i < 32; ++i) dst[i] = f2bf(acc[i]);
}

// ---------- kernel 4: out = q @ W_eff^T + b_out (fp32 out, R15 core) --------
__global__ __launch_bounds__(512, 4) void gemm_out_kernel(const ushort* __restrict__ q,
                                                          const ushort* __restrict__ weff,
                                                          const float* __restrict__ bout,
                                                          float* __restrict__ out) {
  __shared__ ushort lds[36864];  // 72 KiB -> 2 blocks/CU, grid 512 = 1 round
  f32x4 acc[4][4] = {};
  const int row0 = blockIdx.x * 128;
  const int col0 = blockIdx.y * 256;
  const int b = row0 >> 12;  // row0 / 4096
  gemm_core32<512, 512, 16>(q, weff + (size_t)b * 1024 * 512, row0, col0, acc, lds);
  const int l = threadIdx.x & 63;
  const int wid = threadIdx.x >> 6;
  const int wr = wid >> 2, wc = wid & 3;
  const int fr = l & 15, fq = l >> 4;
  #pragma unroll
  for (int m = 0; m < 4; ++m) {
    #pragma unroll
    for (int n = 0; n < 4; ++n) {
      const int c = col0 + wc * 64 + n * 16 + fr;
      const float bb = bout[c];
      #pragma unroll
      for (int j = 0; j < 4; ++j) {
        const int r = row0 + wr * 64 + m * 16 + fq * 4 + j;
        out[(size_t)r * 1024 + c] = acc[m][n][j] + bb;
      }
    }
  }
}

extern "C" void kernel_launch(void* const* d_in, const int* in_sizes, int n_in,
                              void* d_out, int out_size, void* d_ws, size_t ws_size,
                              hipStream_t stream) {
  const float* x    = (const float*)d_in[0];
  const float* Wqkv = (const float*)d_in[1];
  const float* Wout = (const float*)d_in[2];
  const float* bout = (const float*)d_in[3];
  float* out = (float*)d_out;
  char* ws = (char*)d_ws;

  // workspace layout (bytes). part aliases xb (xb dead after gemm_qkv).
  ushort* xb   = (ushort*)(ws);              // 16384*1024*2  = 33554432
  float*  part = (float* )(ws);              // 16*32*4096*4  = 8388608 (alias)
  ushort* wt   = (ushort*)(ws + 33554432);   // 1536*1024*2   = 3145728
  ushort* q    = (ushort*)(ws + 36700160);   // 16384*512*2   = 16777216
  ushort* kT   = (ushort*)(ws + 53477376);   // 32*64*4096*2  = 16777216
  ushort* vT   = (ushort*)(ws + 70254592);   // 32*64*4096*2  = 16777216
  ushort* weff = (ushort*)(ws + 87556096);   // 4*1024*512*2  = 4194304

  prep_kernel<<<3584, 256, 0, stream>>>((const float4*)x, (ushort4*)xb, Wqkv, wt);
  gemm_qkv_kernel<<<dim3(128, 12), 256, 0, stream>>>(xb, wt, q, kT, vT);
  ctx_mfma_kernel<<<dim3(32, 16), 256, 0, stream>>>(kT, vT, part);
  weff_kernel<<<dim3(32, 8), 256, 0, stream>>>(part, Wout, weff);
  gemm_out_kernel<<<dim3(128, 4), 512, 0, stream>>>(q, weff, bout, out);
}

// Round 20
// 127.343 us; speedup vs baseline: 1.1166x; 1.1166x over previous
//
#include <hip/hip_runtime.h>
#include <hip/hip_bf16.h>
#include <cstdint>

typedef __attribute__((ext_vector_type(4))) float f32x4;
typedef __attribute__((ext_vector_type(8))) short bf16x8;

__device__ __forceinline__ ushort f2bf(float f) {
  unsigned u = __builtin_bit_cast(unsigned, f);
  u += 0x7fffu + ((u >> 16) & 1u);
  return (ushort)(u >> 16);
}

__device__ __forceinline__ void gload_lds16(const ushort* g, ushort* l) {
  __builtin_amdgcn_global_load_lds(
      (const __attribute__((address_space(1))) unsigned int*)g,
      (__attribute__((address_space(3))) unsigned int*)l, 16, 0, 0);
}

__device__ __forceinline__ void hard_barrier() {
  __builtin_amdgcn_sched_barrier(0);
  __builtin_amdgcn_s_barrier();
  __builtin_amdgcn_sched_barrier(0);
}

template <int N>
__device__ __forceinline__ void wait_vm() {
  if constexpr (N == 0) asm volatile("s_waitcnt vmcnt(0)" ::: "memory");
  else if constexpr (N == 2) asm volatile("s_waitcnt vmcnt(2)" ::: "memory");
  else if constexpr (N == 3) asm volatile("s_waitcnt vmcnt(3)" ::: "memory");
  else if constexpr (N == 4) asm volatile("s_waitcnt vmcnt(4)" ::: "memory");
  else static_assert(N < 0, "unsupported vmcnt");
}

__device__ __forceinline__ float elu1(float v) {
  return (v > 0.f) ? (v + 1.f) : __expf(v);
}

// ---------- kernel 0: fused prep ----------
__global__ __launch_bounds__(256) void prep_kernel(const float4* __restrict__ x,
                                                   ushort4* __restrict__ xb,
                                                   const float* __restrict__ W,
                                                   ushort* __restrict__ Wt) {
  if (blockIdx.x < 2048) {
    const int n4 = 16384 * 1024 / 4;
    const int stride = 2048 * 256;
    for (int i = blockIdx.x * 256 + threadIdx.x; i < n4; i += stride) {
      float4 f = x[i];
      ushort4 o;
      o.x = f2bf(f.x); o.y = f2bf(f.y); o.z = f2bf(f.z); o.w = f2bf(f.w);
      xb[i] = o;
    }
  } else {
    __shared__ float tile[32][33];
    const int tb = blockIdx.x - 2048;     // 0..1535
    const int n0 = (tb % 48) * 32;
    const int k0 = (tb / 48) * 32;
    const int tx = threadIdx.x & 31;
    const int ty = threadIdx.x >> 5;      // 0..7
    #pragma unroll
    for (int p = 0; p < 4; ++p) {
      int k = k0 + ty + p * 8;
      tile[ty + p * 8][tx] = W[(size_t)k * 1536 + n0 + tx];
    }
    __syncthreads();
    #pragma unroll
    for (int p = 0; p < 4; ++p) {
      int n = n0 + ty + p * 8;
      Wt[(size_t)n * 1024 + k0 + tx] = f2bf(tile[tx][ty + p * 8]);
    }
  }
}

// ============================================================================
// R15 core (measured best: 850 TF, 0 bank conflicts, 2 blocks/CU): 128x256
// tile, 512 thr = 8 waves (2M x 4N), wave tile 64x64, BK=32, 3 slots x 24KB
// = 72 KiB. Pipeline: stage(t+2); compute(t); vmcnt(3); one barrier per tile.
// Swizzle: sig = fq ^ ((fr>>1)&3) (verified conflict-free), staged via
// pre-swizzled global source (rule #21). Constrained optimum of
// {wave-tile reuse x occupancy x register budget x LDS BW} — 9 structural
// variants (R2-R7, R16, R19 tiles/schedules) all regressed.
// ============================================================================
template <int LDA, int LDB, int NT>
__device__ __forceinline__ void gemm_core32(const ushort* __restrict__ A,
                                            const ushort* __restrict__ Bt,
                                            int row0, int col0, f32x4 acc[4][4],
                                            ushort* lds) {
  const int tid = threadIdx.x;
  const int l = tid & 63;
  const int wid = tid >> 6;
  const int fr = l & 15;
  const int fq = l >> 4;
  const int wr = wid >> 2;
  const int wc = wid & 3;

  const int sc = ((tid & 3) ^ ((tid >> 3) & 3)) * 8;  // pre-swizzled source col
  const ushort* aS = A + (size_t)(row0 + (tid >> 2)) * LDA + sc;
  const ushort* bS = Bt + (size_t)(col0 + (tid >> 2)) * LDB + sc;

  auto stage = [&](int t) {
    ushort* base = lds + (t % 3) * 12288 + tid * 8;
    gload_lds16(aS + t * 32, base);
    gload_lds16(bS + t * 32, base + 4096);
    gload_lds16(bS + (size_t)128 * LDB + t * 32, base + 8192);
  };

  const int sig = fq ^ ((fr >> 1) & 3);
  const int aOff = wr * 2048 + fr * 32 + sig * 8;
  const int bOff = 4096 + wc * 2048 + fr * 32 + sig * 8;

  auto compute = [&](int t) {
    const ushort* sb = lds + (t % 3) * 12288;
    bf16x8 av[4], bv[4];
    #pragma unroll
    for (int m = 0; m < 4; ++m) av[m] = *(const bf16x8*)(sb + aOff + m * 512);
    #pragma unroll
    for (int n = 0; n < 4; ++n) bv[n] = *(const bf16x8*)(sb + bOff + n * 512);
    __builtin_amdgcn_s_setprio(1);
    #pragma unroll
    for (int m = 0; m < 4; ++m)
      #pragma unroll
      for (int n = 0; n < 4; ++n)
        acc[m][n] = __builtin_amdgcn_mfma_f32_16x16x32_bf16(av[m], bv[n], acc[m][n], 0, 0, 0);
    __builtin_amdgcn_s_setprio(0);
  };

  stage(0);
  stage(1);
  wait_vm<3>();
  hard_barrier();

  #pragma unroll 3
  for (int t = 0; t < NT; ++t) {
    if (t + 2 < NT) stage(t + 2);
    compute(t);
    if (t + 2 < NT) {
      wait_vm<3>();
      hard_barrier();
    } else if (t + 1 < NT) {
      wait_vm<0>();
      hard_barrier();
    }
  }
}

// ---------- kernel 1: qkv GEMM; epilogue emits q (elu+1), kT (elu+1), vT ----
__global__ __launch_bounds__(512, 4) void gemm_qkv_kernel(const ushort* __restrict__ xb,
                                                          const ushort* __restrict__ wt,
                                                          ushort* __restrict__ q,
                                                          ushort* __restrict__ kT,
                                                          ushort* __restrict__ vT) {
  __shared__ ushort lds[36864];  // 72 KiB -> 2 blocks/CU
  f32x4 acc[4][4] = {};
  const int row0 = blockIdx.x * 128;
  const int col0 = blockIdx.y * 256;
  gemm_core32<1024, 1024, 32>(xb, wt, row0, col0, acc, lds);
  const int l = threadIdx.x & 63;
  const int wid = threadIdx.x >> 6;
  const int wr = wid >> 2, wc = wid & 3;
  const int fr = l & 15, fq = l >> 4;
  #pragma unroll
  for (int m = 0; m < 4; ++m) {
    #pragma unroll
    for (int n = 0; n < 4; ++n) {
      const int c = col0 + wc * 64 + n * 16 + fr;
      const int r0 = row0 + wr * 64 + m * 16 + fq * 4;  // j=0..3 consecutive rows
      if (c < 512) {
        #pragma unroll
        for (int j = 0; j < 4; ++j)
          q[(size_t)(r0 + j) * 512 + c] = f2bf(elu1(acc[m][n][j]));
      } else if (c < 1024) {
        const int d = c - 512;
        const int bh = (r0 >> 12) * 8 + (d >> 6);
        const int nn = r0 & 4095;
        ushort4 o;
        o.x = f2bf(elu1(acc[m][n][0]));
        o.y = f2bf(elu1(acc[m][n][1]));
        o.z = f2bf(elu1(acc[m][n][2]));
        o.w = f2bf(elu1(acc[m][n][3]));
        *(ushort4*)&kT[((size_t)bh * 64 + (d & 63)) * 4096 + nn] = o;
      } else {
        const int d = c - 1024;
        const int bh = (r0 >> 12) * 8 + (d >> 6);
        const int nn = r0 & 4095;
        ushort4 o;
        o.x = f2bf(acc[m][n][0]);
        o.y = f2bf(acc[m][n][1]);
        o.z = f2bf(acc[m][n][2]);
        o.w = f2bf(acc[m][n][3]);
        *(ushort4*)&vT[((size_t)bh * 64 + (d & 63)) * 4096 + nn] = o;
      }
    }
  }
}

// ---------- kernel 2: ctx partials via MFMA; 16 splits (2 blocks/CU) ----------
__global__ __launch_bounds__(256) void ctx_mfma_kernel(const ushort* __restrict__ kT,
                                                       const ushort* __restrict__ vT,
                                                       float* __restrict__ part) {
  __shared__ ushort lds[16384];  // 32 KiB
  const int bh = blockIdx.x;
  const int sp = blockIdx.y;  // 0..15
  const int tid = threadIdx.x;
  const int l = tid & 63, wid = tid >> 6;
  const int fr = l & 15, fq = l >> 4;
  const int wr = wid >> 1, wc = wid & 1;

  const size_t base = (size_t)bh * 64 * 4096 + sp * 256;
  const int srow = tid >> 2;                     // 0..63
  const int lam = (tid & 3) ^ ((tid >> 3) & 3);  // logical 16B slot for phys (tid&3)
  const ushort* aG = kT + base + (size_t)srow * 4096 + lam * 8;
  const ushort* bG = vT + base + (size_t)srow * 4096 + lam * 8;

  auto stage = [&](int t) {
    ushort* d = lds + (t & 3) * 4096 + tid * 8;
    gload_lds16(aG + t * 32, d);
    gload_lds16(bG + t * 32, d + 2048);
  };

  const int sig = fq ^ ((fr >> 1) & 3);
  f32x4 acc[2][2] = {};

  auto compute = [&](int t) {
    const ushort* sb = lds + (t & 3) * 4096;
    bf16x8 av[2], bv[2];
    #pragma unroll
    for (int mm = 0; mm < 2; ++mm)
      av[mm] = *(const bf16x8*)&sb[(wr * 32 + mm * 16 + fr) * 32 + sig * 8];
    #pragma unroll
    for (int nn = 0; nn < 2; ++nn)
      bv[nn] = *(const bf16x8*)&sb[2048 + (wc * 32 + nn * 16 + fr) * 32 + sig * 8];
    #pragma unroll
    for (int mm = 0; mm < 2; ++mm)
      #pragma unroll
      for (int nn = 0; nn < 2; ++nn)
        acc[mm][nn] = __builtin_amdgcn_mfma_f32_16x16x32_bf16(av[mm], bv[nn], acc[mm][nn], 0, 0, 0);
  };

  constexpr int NT = 8;
  stage(0); stage(1); stage(2);
  for (int t = 0; t < NT; ++t) {
    if (t <= NT - 3) wait_vm<4>();
    else if (t == NT - 2) wait_vm<2>();
    else wait_vm<0>();
    hard_barrier();
    compute(t);
    hard_barrier();
    if (t + 3 < NT) stage(t + 3);
  }

  float* dst = part + ((size_t)sp * 32 + bh) * 4096;
  #pragma unroll
  for (int mm = 0; mm < 2; ++mm)
    #pragma unroll
    for (int nn = 0; nn < 2; ++nn)
      #pragma unroll
      for (int j = 0; j < 4; ++j)
        dst[(wr * 32 + mm * 16 + fq * 4 + j) * 64 + wc * 32 + nn * 16 + fr] = acc[mm][nn][j];
}

// ---------- kernel 3: W_eff^T (folds the 16-way split reduction) ----------
__global__ __launch_bounds__(256) void weff_kernel(const float* __restrict__ part,
                                                   const float* __restrict__ Wout,
                                                   ushort* __restrict__ weff) {
  const int bh = blockIdx.x;  // b*8+h
  const int h = bh & 7;
  const int m0 = blockIdx.y * 128;
  const int t = threadIdx.x;
  __shared__ float cs[64 * 64];
  __shared__ float ws[64][128];
  #pragma unroll
  for (int p = 0; p < 4; ++p) {
    const int idx = p * 1024 + t * 4;
    f32x4 s = {};
    #pragma unroll
    for (int sp = 0; sp < 16; ++sp)
      s += *(const f32x4*)&part[(size_t)sp * 131072 + (size_t)bh * 4096 + idx];
    *(f32x4*)&cs[idx] = s;
  }
  #pragma unroll
  for (int p = 0; p < 8; ++p) {
    const int e = (t >> 5) + p * 8;
    const int c = (t & 31) * 4;
    *(float4*)&ws[e][c] = *(const float4*)&Wout[(size_t)(h * 64 + e) * 1024 + m0 + c];
  }
  __syncthreads();
  const int m = t & 127;
  const int dh = (t >> 7) * 32;
  float acc[32] = {};
  for (int e = 0; e < 64; ++e) {
    const float w = ws[e][m];
    #pragma unroll
    for (int i = 0; i < 32; ++i)
      acc[i] += cs[(dh + i) * 64 + e] * w;
  }
  ushort* dst = weff + ((size_t)(bh >> 3) * 1024 + m0 + m) * 512 + h * 64 + dh;
  #pragma unroll
  for (int i = 0; i < 32; ++i) dst[i] = f2bf(acc[i]);
}

// ---------- kernel 4: out = q @ W_eff^T + b_out (fp32 out) ----------
__global__ __launch_bounds__(512, 4) void gemm_out_kernel(const ushort* __restrict__ q,
                                                          const ushort* __restrict__ weff,
                                                          const float* __restrict__ bout,
                                                          float* __restrict__ out) {
  __shared__ ushort lds[36864];  // 72 KiB -> 2 blocks/CU, grid 512 = 1 round
  f32x4 acc[4][4] = {};
  const int row0 = blockIdx.x * 128;
  const int col0 = blockIdx.y * 256;
  const int b = row0 >> 12;  // row0 / 4096
  gemm_core32<512, 512, 16>(q, weff + (size_t)b * 1024 * 512, row0, col0, acc, lds);
  const int l = threadIdx.x & 63;
  const int wid = threadIdx.x >> 6;
  const int wr = wid >> 2, wc = wid & 3;
  const int fr = l & 15, fq = l >> 4;
  #pragma unroll
  for (int m = 0; m < 4; ++m) {
    #pragma unroll
    for (int n = 0; n < 4; ++n) {
      const int c = col0 + wc * 64 + n * 16 + fr;
      const float bb = bout[c];
      #pragma unroll
      for (int j = 0; j < 4; ++j) {
        const int r = row0 + wr * 64 + m * 16 + fq * 4 + j;
        out[(size_t)r * 1024 + c] = acc[m][n][j] + bb;
      }
    }
  }
}

extern "C" void kernel_launch(void* const* d_in, const int* in_sizes, int n_in,
                              void* d_out, int out_size, void* d_ws, size_t ws_size,
                              hipStream_t stream) {
  const float* x    = (const float*)d_in[0];
  const float* Wqkv = (const float*)d_in[1];
  const float* Wout = (const float*)d_in[2];
  const float* bout = (const float*)d_in[3];
  float* out = (float*)d_out;
  char* ws = (char*)d_ws;

  // workspace layout (bytes). part aliases xb (xb dead after gemm_qkv).
  ushort* xb   = (ushort*)(ws);              // 16384*1024*2  = 33554432
  float*  part = (float* )(ws);              // 16*32*4096*4  = 8388608 (alias)
  ushort* wt   = (ushort*)(ws + 33554432);   // 1536*1024*2   = 3145728
  ushort* q    = (ushort*)(ws + 36700160);   // 16384*512*2   = 16777216
  ushort* kT   = (ushort*)(ws + 53477376);   // 32*64*4096*2  = 16777216
  ushort* vT   = (ushort*)(ws + 70254592);   // 32*64*4096*2  = 16777216
  ushort* weff = (ushort*)(ws + 87556096);   // 4*1024*512*2  = 4194304

  prep_kernel<<<3584, 256, 0, stream>>>((const float4*)x, (ushort4*)xb, Wqkv, wt);
  gemm_qkv_kernel<<<dim3(128, 6), 512, 0, stream>>>(xb, wt, q, kT, vT);
  ctx_mfma_kernel<<<dim3(32, 16), 256, 0, stream>>>(kT, vT, part);
  weff_kernel<<<dim3(32, 8), 256, 0, stream>>>(part, Wout, weff);
  gemm_out_kernel<<<dim3(128, 4), 512, 0, stream>>>(q, weff, bout, out);
}